// Round 8
// baseline (2655.034 us; speedup 1.0000x reference)
//
#include <hip/hip_runtime.h>
#include <cstdint>

// ---------------------------------------------------------------------------
// 2-layer tanh RNN (B=256,S=2048,D=64,H=256).
// R11 post-mortem (decisive): halving stage-A work (g moved off-path) left the
// ~1000ns step UNCHANGED -> step time tracks LDS-pipe traffic between
// barriers, not MFMA/VALU count. Decomposition @2230cy: 64 ds_read_b128/WG
// (~770cy @12cy, inherent to 8-wave broadcast) + 128 ds_write_b16 (~740cy)
// + issue/latency/barrier. R5(128 reads)=3445cy, R6/R7(64)=2230 fits.
// R12 = R7 2-stage (best verified, 1903us kernel) + in-place step trims:
//   1. sth4 DPP pair-packed h-writes (16 b16 -> 8 b32 per wave; write pipe
//      ~740->~370cy). Verified in R8/R10/R11 with identical addressing.
//   2. split-K=2 accumulators (A: 8 chains, B: 4): dep-MFMA depth 8->4,
//      breadth hides latency; f32 reassociation only.
// No G stage, no h0 persist (removes R11's 250us drain + 250MB HBM writes).
// All converters f2bf manual-RNE (R9 lesson).
// ---------------------------------------------------------------------------

#define S_LEN 2048
#define DIN   64
#define HDIM  256
#define CH    64        // chunk size (steps per cross-stage sync)

typedef __attribute__((ext_vector_type(8))) short bf16x8;
typedef __attribute__((ext_vector_type(4))) float f32x4;

__device__ __forceinline__ short f2bf(float f) {
  unsigned u = __builtin_bit_cast(unsigned, f);
  u += 0x7FFFu + ((u >> 16) & 1u);           // RNE
  return (short)(u >> 16);
}
__device__ __forceinline__ float bf2f(unsigned short h) {
  return __builtin_bit_cast(float, ((unsigned)h) << 16);
}
__device__ __forceinline__ bf16x8 cvt8(f32x4 a, f32x4 b) {
  bf16x8 r;
  r[0]=f2bf(a[0]); r[1]=f2bf(a[1]); r[2]=f2bf(a[2]); r[3]=f2bf(a[3]);
  r[4]=f2bf(b[0]); r[5]=f2bf(b[1]); r[6]=f2bf(b[2]); r[7]=f2bf(b[3]);
  return r;
}
__device__ __forceinline__ bf16x8 load8cvt(const float* p) {
  f32x4 a = *(const f32x4*)p;
  f32x4 b = *(const f32x4*)(p + 4);
  return cvt8(a, b);
}
__device__ __forceinline__ f32x4 mfma16(bf16x8 a, bf16x8 b, f32x4 c) {
  return __builtin_amdgcn_mfma_f32_16x16x32_bf16(a, b, c, 0, 0, 0);
}
__device__ __forceinline__ float fast_tanh(float x) {
  float e = __expf(2.0f * x);
  float r = __builtin_amdgcn_rcpf(1.0f + e);
  return 1.0f - 2.0f * r;
}
__device__ __forceinline__ f32x4 tanh4(f32x4 a) {
  f32x4 r;
  r[0] = fast_tanh(a[0]); r[1] = fast_tanh(a[1]);
  r[2] = fast_tanh(a[2]); r[3] = fast_tanh(a[3]);
  return r;
}
__device__ __forceinline__ int frag_off(int k, int m) {
  return ((k >> 5) << 10) | (((k >> 3) & 3) << 8) | (m << 4) | ((k & 7) << 1);
}
__device__ __forceinline__ f32x4 unpk4(uint2 v) {
  f32x4 a;
  a[0] = __builtin_bit_cast(float, v.x << 16);
  a[1] = __builtin_bit_cast(float, v.x & 0xFFFF0000u);
  a[2] = __builtin_bit_cast(float, v.y << 16);
  a[3] = __builtin_bit_cast(float, v.y & 0xFFFF0000u);
  return a;
}
__device__ __forceinline__ uint2 pk4(f32x4 a) {
  uint2 p;
  p.x = (unsigned)(unsigned short)f2bf(a[0]) | ((unsigned)(unsigned short)f2bf(a[1]) << 16);
  p.y = (unsigned)(unsigned short)f2bf(a[2]) | ((unsigned)(unsigned short)f2bf(a[3]) << 16);
  return p;
}
__device__ __forceinline__ unsigned ld_acq(unsigned* p) {
  return __hip_atomic_load(p, __ATOMIC_ACQUIRE, __HIP_MEMORY_SCOPE_AGENT);
}
__device__ __forceinline__ void st_rlx(unsigned* p, unsigned v) {
  __hip_atomic_store(p, v, __ATOMIC_RELAXED, __HIP_MEMORY_SCOPE_AGENT);
}
// LDS-only workgroup barrier: drains ds ops but leaves global loads/stores in
// flight (per-step cross-wave hazard is the LDS h ping/pong only).
__device__ __forceinline__ void bar_lds() {
  asm volatile("s_waitcnt lgkmcnt(0)" ::: "memory");
  __builtin_amdgcn_s_barrier();
}
// h-store: lanes l and l^1 hold bf16 for k and k^1 of the same row m; their
// frag addrs are 2B apart. DPP quad_perm(1,0,3,2) swaps the pair in-register;
// even lane writes one packed b32. mov_dpp is convergent. (R8/R10/R11-verified.)
__device__ __forceinline__ void sth4(char* base, int wb, f32x4 a, int l) {
#pragma unroll
  for (int r = 0; r < 4; ++r) {
    unsigned own = (unsigned)(unsigned short)f2bf(a[r]);
    unsigned nb = (unsigned)__builtin_amdgcn_mov_dpp((int)own, 0xB1, 0xF, 0xF, true);
    if ((l & 1) == 0)
      *(unsigned*)(base + wb + r * 16) = own | (nb << 16);
  }
}

__global__ void zero_flags(unsigned* f) {
  if (threadIdx.x < 64) f[threadIdx.x] = 0u;
}

// ============ pre-pass: pre0[tile][t][ntile][lane] = x W_ih0^T + b (C-layout)
__global__ void __launch_bounds__(256)
x_proj(const float* __restrict__ x, const float* __restrict__ Wih0,
       const float* __restrict__ bih0, const float* __restrict__ bhh0,
       uint2* __restrict__ pre0) {
  const int tid = threadIdx.x, w = tid >> 6, l = tid & 63;
  const int lm = l & 15, lq = l >> 4;
  const int tile = blockIdx.x, tch = blockIdx.y;

  bf16x8 wih[4][2]; float bias[4];
#pragma unroll
  for (int i = 0; i < 4; ++i) {
    int n = ((w * 4 + i) << 4) + lm;
    wih[i][0] = load8cvt(Wih0 + n * DIN + lq * 8);
    wih[i][1] = load8cvt(Wih0 + n * DIN + 32 + lq * 8);
    bias[i] = bih0[n] + bhh0[n];
  }
  const float* xb = x + (size_t)(tile * 16 + lm) * (S_LEN * DIN) + lq * 8;
  for (int tt = 0; tt < 16; ++tt) {
    int t = tch * 16 + tt;
    const float* xp = xb + (size_t)t * DIN;
    bf16x8 xa0 = load8cvt(xp);
    bf16x8 xa1 = load8cvt(xp + 32);
    uint2* dst = pre0 + ((size_t)(tile * S_LEN + t) * 16 + w * 4) * 64 + l;
#pragma unroll
    for (int i = 0; i < 4; ++i) {
      f32x4 a = {bias[i], bias[i], bias[i], bias[i]};
      a = mfma16(xa0, wih[i][0], a);
      a = mfma16(xa1, wih[i][1], a);
      dst[(size_t)i * 64] = pk4(a);
    }
  }
}

// ============ layer-pipelined recurrence: 32 WGs x 512 thr ==================
// Stage A (WG 0-15):  h0 recurrence + g=h0@Wih1^T+b1 (shares h0 LDS reads),
//                     g in-place over consumed pre0; flag every CH steps.
// Stage B (WG 16-31): h1 recurrence from g; epilogue sigmoid@W_out.
// LDS: h ping 0 / pong 8192; B epilogue scratch 16384.
__global__ void __launch_bounds__(512, 2)
rnn_pipe2s(const float* __restrict__ Whh0, const float* __restrict__ Wih1,
           const float* __restrict__ Whh1, const float* __restrict__ bih1,
           const float* __restrict__ bhh1, const float* __restrict__ Wout,
           const float* __restrict__ bout, uint2* __restrict__ pre0,
           unsigned* __restrict__ flags, float* __restrict__ out) {
  __shared__ __align__(16) char smem[17408];

  const int tid = threadIdx.x, w = tid >> 6, l = tid & 63;
  const int lm = l & 15, lq = l >> 4;
  const int role = blockIdx.x >> 4;       // 0=A (layer0+g), 1=B (layer1)
  const int tile = blockIdx.x & 15;       // A(t),B(t) same XCD (%8)

  const int lbase = l << 4;
  const int wbase = frag_off(w * 32 + lm, lq << 2);
  uint2* pb = pre0 + (size_t)tile * (S_LEN * 1024) + w * 128 + l;
  unsigned* flag = flags + tile;

  const f32x4 zero4 = {0.f, 0.f, 0.f, 0.f};

  if (role == 0) {
    // ================= Stage A: h0 recurrence + g producer ==================
    bf16x8 whh0[2][8], wih1[2][8];
    float bias1[2];
#pragma unroll
    for (int i = 0; i < 2; ++i) {
      int n = ((w * 2 + i) << 4) + lm;
#pragma unroll
      for (int kt = 0; kt < 8; ++kt) {
        whh0[i][kt] = load8cvt(Whh0 + n * HDIM + kt * 32 + lq * 8);
        wih1[i][kt] = load8cvt(Wih1 + n * HDIM + kt * 32 + lq * 8);
      }
      bias1[i] = bih1[n] + bhh1[n];
    }
    uint2 bufA[2], bufB[2];
    bufA[0] = pb[0];    bufA[1] = pb[64];        // pre[0]
    bufB[0] = pb[1024]; bufB[1] = pb[1024 + 64]; // pre[1]

    // phase 0 (peeled): h0[0] = tanh(pre[0]) into parity-0 buffer
    {
      sth4(smem, wbase, tanh4(unpk4(bufA[0])), l);
      sth4(smem, wbase + 512, tanh4(unpk4(bufA[1])), l);
      const uint2* np = pb + (size_t)2 * 1024;   // prefetch pre[2]
      bufA[0] = np[0]; bufA[1] = np[64];
      bar_lds();
    }

    // phase p: h0[p] = tanh(pre[p] + h0[p-1]Whh0^T), g[p-1] = h0[p-1]Wih1^T+b1
    // split-K=2: low half kt=0..3, high half kt=4..7, combined at the end.
    auto phaseA = [&](int p, int pbit, uint2 (&buf)[2]) {
      const int h0r = (pbit ^ 1) * 8192;
      const int h0w = pbit * 8192;
      f32x4 a0 = unpk4(buf[0]), a1 = unpk4(buf[1]);
      f32x4 a0h = zero4, a1h = zero4;
      f32x4 g0 = {bias1[0], bias1[0], bias1[0], bias1[0]};
      f32x4 g1 = {bias1[1], bias1[1], bias1[1], bias1[1]};
      f32x4 g0h = zero4, g1h = zero4;
#pragma unroll
      for (int kt = 0; kt < 4; ++kt) {           // shared h0[p-1] read
        bf16x8 hfL = *(const bf16x8*)(smem + h0r + kt * 1024 + lbase);
        bf16x8 hfH = *(const bf16x8*)(smem + h0r + (kt + 4) * 1024 + lbase);
        a0  = mfma16(hfL, whh0[0][kt],     a0);
        a1  = mfma16(hfL, whh0[1][kt],     a1);
        g0  = mfma16(hfL, wih1[0][kt],     g0);
        g1  = mfma16(hfL, wih1[1][kt],     g1);
        a0h = mfma16(hfH, whh0[0][kt + 4], a0h);
        a1h = mfma16(hfH, whh0[1][kt + 4], a1h);
        g0h = mfma16(hfH, wih1[0][kt + 4], g0h);
        g1h = mfma16(hfH, wih1[1][kt + 4], g1h);
      }
      a0 = a0 + a0h; a1 = a1 + a1h;
      g0 = g0 + g0h; g1 = g1 + g1h;
      {                                          // prefetch pre[p+2] (clamped)
        int tn = (p + 2 < S_LEN) ? p + 2 : S_LEN - 1;
        const uint2* np = pb + (size_t)tn * 1024;
        buf[0] = np[0]; buf[1] = np[64];
      }
      sth4(smem + h0w, wbase, tanh4(a0), l);     // write h0[p] to LDS
      sth4(smem + h0w, wbase + 512, tanh4(a1), l);
      {                                          // g[p-1] in-place over pre0
        uint2* gd = pb + (size_t)(p - 1) * 1024;
        gd[0] = pk4(g0); gd[64] = pk4(g1);
      }
      if ((p & (CH - 1)) == 0) {                 // chunk p/CH-1 complete:
        __builtin_amdgcn_fence(__ATOMIC_RELEASE, "agent");  // drains stores
        __syncthreads();                         // all waves fenced
        if (tid == 0) st_rlx(flag, (unsigned)(p >> 6));
      } else {
        bar_lds();                               // LDS-only handoff
      }
    };

    for (int p = 1; p + 1 < S_LEN; p += 2) {
      phaseA(p, 1, bufB);
      phaseA(p + 1, 0, bufA);
    }
    phaseA(S_LEN - 1, 1, bufB);                  // p = 2047

    // tail: g[S-1] = h0[S-1]Wih1^T + b1  (h0[2047] at parity 1; cold path)
    {
      f32x4 g0 = {bias1[0], bias1[0], bias1[0], bias1[0]};
      f32x4 g1 = {bias1[1], bias1[1], bias1[1], bias1[1]};
#pragma unroll
      for (int kt = 0; kt < 8; ++kt) {
        bf16x8 hf = *(const bf16x8*)(smem + 8192 + kt * 1024 + lbase);
        g0 = mfma16(hf, wih1[0][kt], g0);
        g1 = mfma16(hf, wih1[1][kt], g1);
      }
      uint2* gd = pb + (size_t)(S_LEN - 1) * 1024;
      gd[0] = pk4(g0); gd[64] = pk4(g1);
      __builtin_amdgcn_fence(__ATOMIC_RELEASE, "agent");
      __syncthreads();
      if (tid == 0) st_rlx(flag, (unsigned)(S_LEN / CH));   // = 32
    }

  } else {
    // ================= Stage B: h1 recurrence + output ======================
    bf16x8 whh1[2][8];
#pragma unroll
    for (int i = 0; i < 2; ++i) {
      int n = ((w * 2 + i) << 4) + lm;
#pragma unroll
      for (int kt = 0; kt < 8; ++kt)
        whh1[i][kt] = load8cvt(Whh1 + n * HDIM + kt * 32 + lq * 8);
    }
    // zero h1[-1] (parity-1 buffer at 8192): 512 thr x 16B = 8KB
    ((f32x4*)(smem + 8192))[tid] = zero4;
    __syncthreads();

    uint2 gcur[2], gnxt[2];
    unsigned have = 0;
    unsigned budget = 4000000u;                  // bounded spin; never hang

    auto stepB = [&](int t, int pbit) {
      const int h1r = (pbit ^ 1) * 8192;
      const int h1w = pbit * 8192;
      const bool pf = ((t & (CH - 1)) != CH - 1);  // next g within this chunk
      if (pf) {
        const uint2* np = pb + (size_t)(t + 1) * 1024;
        gnxt[0] = np[0]; gnxt[1] = np[64];
      }
      f32x4 c0 = unpk4(gcur[0]), c1 = unpk4(gcur[1]);
      f32x4 c0h = zero4, c1h = zero4;
#pragma unroll
      for (int kt = 0; kt < 4; ++kt) {
        bf16x8 hfL = *(const bf16x8*)(smem + h1r + kt * 1024 + lbase);
        bf16x8 hfH = *(const bf16x8*)(smem + h1r + (kt + 4) * 1024 + lbase);
        c0  = mfma16(hfL, whh1[0][kt],     c0);
        c1  = mfma16(hfL, whh1[1][kt],     c1);
        c0h = mfma16(hfH, whh1[0][kt + 4], c0h);
        c1h = mfma16(hfH, whh1[1][kt + 4], c1h);
      }
      c0 = c0 + c0h; c1 = c1 + c1h;
      sth4(smem + h1w, wbase, tanh4(c0), l);
      sth4(smem + h1w, wbase + 512, tanh4(c1), l);
      if (pf) { gcur[0] = gnxt[0]; gcur[1] = gnxt[1]; }
      bar_lds();                                   // LDS-only handoff
    };

    for (int c = 0; c < S_LEN / CH; ++c) {
      while (have < (unsigned)(c + 1)) {           // per-chunk acquire wait
        have = ld_acq(flag);
        if (have < (unsigned)(c + 1)) {
          __builtin_amdgcn_s_sleep(8);
          if (--budget == 0u) { have = (unsigned)(c + 1); }
        }
      }
      const int t0 = c * CH;
      { const uint2* np = pb + (size_t)t0 * 1024; gcur[0] = np[0]; gcur[1] = np[64]; }
      for (int tt = 0; tt < CH; tt += 2) {
        stepB(t0 + tt, 0);
        stepB(t0 + tt + 1, 1);
      }
    }

    // epilogue: out = sigmoid(h1[S-1] @ W_out^T + b_out); h1[2047] at 8192
    if (tid < 256) {
      int m = tid >> 4, j = tid & 15;
      float s = 0.f;
#pragma unroll
      for (int kk = 0; kk < 16; ++kk) {
        int k = j * 16 + kk;
        s += bf2f(*(unsigned short*)(smem + 8192 + frag_off(k, m))) * Wout[k];
      }
      ((float*)(smem + 16384))[(m << 4) + j] = s;
    }
    __syncthreads();
    if (tid < 16) {
      float s = 0.f;
#pragma unroll
      for (int j = 0; j < 16; ++j) s += ((float*)(smem + 16384))[(tid << 4) + j];
      s += bout[0];
      out[(tile << 4) + tid] = 1.f / (1.f + __expf(-s));
    }
  }
}

// ============ fallback (ws too small for flags): R5 single-stage ============
__global__ void __launch_bounds__(512, 2)
rnn_pre8(const float* __restrict__ Whh0, const float* __restrict__ Wih1,
         const float* __restrict__ Whh1, const float* __restrict__ bih1,
         const float* __restrict__ bhh1, const float* __restrict__ Wout,
         const float* __restrict__ bout, const uint2* __restrict__ pre0,
         float* __restrict__ out) {
  __shared__ __align__(16) char smem[33792];

  const int tid = threadIdx.x, w = tid >> 6, l = tid & 63;
  const int lm = l & 15, lq = l >> 4;
  const int tile = blockIdx.x;

  bf16x8 whh0[2][8], wih1[2][8], whh1[2][8];
  float bias1[2];
#pragma unroll
  for (int i = 0; i < 2; ++i) {
    int n = ((w * 2 + i) << 4) + lm;
#pragma unroll
    for (int kt = 0; kt < 8; ++kt) {
      whh0[i][kt] = load8cvt(Whh0 + n * HDIM + kt * 32 + lq * 8);
      wih1[i][kt] = load8cvt(Wih1 + n * HDIM + kt * 32 + lq * 8);
      whh1[i][kt] = load8cvt(Whh1 + n * HDIM + kt * 32 + lq * 8);
    }
    bias1[i] = bih1[n] + bhh1[n];
  }
  ((f32x4*)(smem + 24576))[tid] = (f32x4){0.f, 0.f, 0.f, 0.f};

  const int lbase = l << 4;
  const int wbase = frag_off(w * 32 + lm, lq << 2);
  const uint2* pbase = pre0 + (size_t)tile * (S_LEN * 1024) + w * 128 + l;
  uint2 bufA[2], bufB[2];
  bufA[0] = pbase[0];    bufA[1] = pbase[64];
  bufB[0] = pbase[1024]; bufB[1] = pbase[1024 + 64];

  {
#pragma unroll
    for (int i = 0; i < 2; ++i) {
      f32x4 a = unpk4(bufA[i]);
#pragma unroll
      for (int r = 0; r < 4; ++r)
        *(short*)(smem + wbase + i * 512 + r * 16) = f2bf(fast_tanh(a[r]));
    }
    const uint2* np = pbase + (size_t)2 * 1024;
    bufA[0] = np[0]; bufA[1] = np[64];
    bar_lds();
  }

  auto phase = [&](int p, int pbit, uint2 (&buf)[2]) {
    const int h0r_o = (pbit ^ 1) * 8192;
    const int h0w_o = pbit * 8192;
    const int h1r_o = 16384 + pbit * 8192;
    const int h1w_o = 16384 + (pbit ^ 1) * 8192;

    f32x4 a0 = unpk4(buf[0]), a1 = unpk4(buf[1]);
    f32x4 c0 = {bias1[0], bias1[0], bias1[0], bias1[0]};
    f32x4 c1 = {bias1[1], bias1[1], bias1[1], bias1[1]};
#pragma unroll
    for (int kt = 0; kt < 8; ++kt) {
      bf16x8 hf = *(const bf16x8*)(smem + h0r_o + kt * 1024 + lbase);
      a0 = mfma16(hf, whh0[0][kt], a0);
      a1 = mfma16(hf, whh0[1][kt], a1);
      c0 = mfma16(hf, wih1[0][kt], c0);
      c1 = mfma16(hf, wih1[1][kt], c1);
    }
#pragma unroll
    for (int kt = 0; kt < 8; ++kt) {
      bf16x8 hf = *(const bf16x8*)(smem + h1r_o + kt * 1024 + lbase);
      c0 = mfma16(hf, whh1[0][kt], c0);
      c1 = mfma16(hf, whh1[1][kt], c1);
    }
#pragma unroll
    for (int i = 0; i < 2; ++i) {
      f32x4 a = i ? a1 : a0;
      f32x4 c = i ? c1 : c0;
#pragma unroll
      for (int r = 0; r < 4; ++r) {
        *(short*)(smem + h0w_o + wbase + i * 512 + r * 16) = f2bf(fast_tanh(a[r]));
        *(short*)(smem + h1w_o + wbase + i * 512 + r * 16) = f2bf(fast_tanh(c[r]));
      }
    }
    {
      int tn = (p + 2 < S_LEN) ? p + 2 : S_LEN - 1;
      const uint2* np = pbase + (size_t)tn * 1024;
      buf[0] = np[0]; buf[1] = np[64];
    }
    bar_lds();
  };

  for (int p = 1; p + 1 < S_LEN; p += 2) {
    phase(p, 1, bufB);
    phase(p + 1, 0, bufA);
  }
  phase(S_LEN - 1, 1, bufB);

  {
    f32x4 c0 = {bias1[0], bias1[0], bias1[0], bias1[0]};
    f32x4 c1 = {bias1[1], bias1[1], bias1[1], bias1[1]};
#pragma unroll
    for (int kt = 0; kt < 8; ++kt) {
      bf16x8 hf = *(const bf16x8*)(smem + 8192 + kt * 1024 + lbase);
      c0 = mfma16(hf, wih1[0][kt], c0);
      c1 = mfma16(hf, wih1[1][kt], c1);
    }
#pragma unroll
    for (int kt = 0; kt < 8; ++kt) {
      bf16x8 hf = *(const bf16x8*)(smem + 16384 + kt * 1024 + lbase);
      c0 = mfma16(hf, whh1[0][kt], c0);
      c1 = mfma16(hf, whh1[1][kt], c1);
    }
#pragma unroll
    for (int i = 0; i < 2; ++i) {
      f32x4 c = i ? c1 : c0;
#pragma unroll
      for (int r = 0; r < 4; ++r)
        *(short*)(smem + 24576 + wbase + i * 512 + r * 16) = f2bf(fast_tanh(c[r]));
    }
    __syncthreads();
  }

  if (tid < 256) {
    int m = tid >> 4, j = tid & 15;
    float s = 0.f;
#pragma unroll
    for (int kk = 0; kk < 16; ++kk) {
      int k = j * 16 + kk;
      s += bf2f(*(unsigned short*)(smem + 24576 + frag_off(k, m))) * Wout[k];
    }
    ((float*)(smem + 32768))[(m << 4) + j] = s;
  }
  __syncthreads();
  if (tid < 16) {
    float s = 0.f;
#pragma unroll
    for (int j = 0; j < 16; ++j) s += ((float*)(smem + 32768))[(tid << 4) + j];
    s += bout[0];
    out[(tile << 4) + tid] = 1.f / (1.f + __expf(-s));
  }
}

extern "C" void kernel_launch(void* const* d_in, const int* in_sizes, int n_in,
                              void* d_out, int out_size, void* d_ws, size_t ws_size,
                              hipStream_t stream) {
  (void)in_sizes; (void)n_in; (void)out_size;
  const float* x    = (const float*)d_in[0];
  const float* Wih0 = (const float*)d_in[1];
  const float* Whh0 = (const float*)d_in[2];
  const float* bih0 = (const float*)d_in[3];
  const float* bhh0 = (const float*)d_in[4];
  const float* Wih1 = (const float*)d_in[5];
  const float* Whh1 = (const float*)d_in[6];
  const float* bih1 = (const float*)d_in[7];
  const float* bhh1 = (const float*)d_in[8];
  const float* Wout = (const float*)d_in[9];
  const float* bout = (const float*)d_in[10];

  const size_t PRE_BYTES = (size_t)16 * S_LEN * 16 * 64 * 8;  // 268 MB

  x_proj<<<dim3(16, 128), dim3(256), 0, stream>>>(x, Wih0, bih0, bhh0,
                                                  (uint2*)d_ws);
  if (ws_size >= PRE_BYTES + 4096) {
    unsigned* flags = (unsigned*)((char*)d_ws + PRE_BYTES);
    zero_flags<<<dim3(1), dim3(64), 0, stream>>>(flags);
    rnn_pipe2s<<<dim3(32), dim3(512), 0, stream>>>(
        Whh0, Wih1, Whh1, bih1, bhh1, Wout, bout, (uint2*)d_ws, flags,
        (float*)d_out);
  } else {
    rnn_pre8<<<dim3(16), dim3(512), 0, stream>>>(
        Whh0, Wih1, Whh1, bih1, bhh1, Wout, bout, (const uint2*)d_ws,
        (float*)d_out);
  }
}

// Round 9
// 2138.214 us; speedup vs baseline: 1.2417x; 1.2417x over previous
//
#include <hip/hip_runtime.h>
#include <cstdint>

// ---------------------------------------------------------------------------
// 2-layer tanh RNN (B=256,S=2048,D=64,H=256).
// R12 post-mortem: BOTH trims refuted vs R7 (1903us). (1) sth4 DPP pack:
// b32@32lanes moves the same 128B/instr as b16@64lanes -> no pipe win, and
// DPP hazard NOPs + exec-mask dance cost on the serial path. (2) split-K=2:
// +32 VGPR acc pressure, and MFMA count provably doesn't set step time
// (R11: half the MFMAs, same step). Scalar b16 h-writes stay.
// R13: recurrence reverted to byte-exact R7 (best verified). Remaining slack
// attacked off the serial path: x_proj's x-loads were uncoalesced (16 batch
// rows, 512KB apart, 32B per lane chunk) -> ~260us vs ~80us floor. Now stages
// x through LDS: per slab, 16 rows x 2KB contiguous coalesced dwordx4 loads,
// then A-fragments read from padded LDS (row stride 516 floats, same quad
// aliasing class as the verified frag layout). Same mfma/pk4 -> bit-identical
// output. All converters f2bf manual-RNE (R9 lesson).
// ---------------------------------------------------------------------------

#define S_LEN 2048
#define DIN   64
#define HDIM  256
#define CH    64        // chunk size (steps per cross-stage sync)

typedef __attribute__((ext_vector_type(8))) short bf16x8;
typedef __attribute__((ext_vector_type(4))) float f32x4;

__device__ __forceinline__ short f2bf(float f) {
  unsigned u = __builtin_bit_cast(unsigned, f);
  u += 0x7FFFu + ((u >> 16) & 1u);           // RNE
  return (short)(u >> 16);
}
__device__ __forceinline__ float bf2f(unsigned short h) {
  return __builtin_bit_cast(float, ((unsigned)h) << 16);
}
__device__ __forceinline__ bf16x8 cvt8(f32x4 a, f32x4 b) {
  bf16x8 r;
  r[0]=f2bf(a[0]); r[1]=f2bf(a[1]); r[2]=f2bf(a[2]); r[3]=f2bf(a[3]);
  r[4]=f2bf(b[0]); r[5]=f2bf(b[1]); r[6]=f2bf(b[2]); r[7]=f2bf(b[3]);
  return r;
}
__device__ __forceinline__ bf16x8 load8cvt(const float* p) {
  f32x4 a = *(const f32x4*)p;
  f32x4 b = *(const f32x4*)(p + 4);
  return cvt8(a, b);
}
__device__ __forceinline__ f32x4 mfma16(bf16x8 a, bf16x8 b, f32x4 c) {
  return __builtin_amdgcn_mfma_f32_16x16x32_bf16(a, b, c, 0, 0, 0);
}
__device__ __forceinline__ float fast_tanh(float x) {
  float e = __expf(2.0f * x);
  float r = __builtin_amdgcn_rcpf(1.0f + e);
  return 1.0f - 2.0f * r;
}
__device__ __forceinline__ int frag_off(int k, int m) {
  return ((k >> 5) << 10) | (((k >> 3) & 3) << 8) | (m << 4) | ((k & 7) << 1);
}
__device__ __forceinline__ f32x4 unpk4(uint2 v) {
  f32x4 a;
  a[0] = __builtin_bit_cast(float, v.x << 16);
  a[1] = __builtin_bit_cast(float, v.x & 0xFFFF0000u);
  a[2] = __builtin_bit_cast(float, v.y << 16);
  a[3] = __builtin_bit_cast(float, v.y & 0xFFFF0000u);
  return a;
}
__device__ __forceinline__ uint2 pk4(f32x4 a) {
  uint2 p;
  p.x = (unsigned)(unsigned short)f2bf(a[0]) | ((unsigned)(unsigned short)f2bf(a[1]) << 16);
  p.y = (unsigned)(unsigned short)f2bf(a[2]) | ((unsigned)(unsigned short)f2bf(a[3]) << 16);
  return p;
}
__device__ __forceinline__ unsigned ld_acq(unsigned* p) {
  return __hip_atomic_load(p, __ATOMIC_ACQUIRE, __HIP_MEMORY_SCOPE_AGENT);
}
__device__ __forceinline__ void st_rlx(unsigned* p, unsigned v) {
  __hip_atomic_store(p, v, __ATOMIC_RELAXED, __HIP_MEMORY_SCOPE_AGENT);
}
// LDS-only workgroup barrier: drains ds ops but leaves global loads/stores in
// flight (per-step cross-wave hazard is the LDS h ping/pong only).
__device__ __forceinline__ void bar_lds() {
  asm volatile("s_waitcnt lgkmcnt(0)" ::: "memory");
  __builtin_amdgcn_s_barrier();
}

__global__ void zero_flags(unsigned* f) {
  if (threadIdx.x < 64) f[threadIdx.x] = 0u;
}

// ============ pre-pass: pre0[tile][t][ntile][lane] = x W_ih0^T + b (C-layout)
// v2: LDS-staged. Per slab of 8 t's: coalesced load of x[16 rows][8t][64d]
// (2KB contiguous per row), then frag-pattern reads from padded LDS.
__global__ void __launch_bounds__(256)
x_proj(const float* __restrict__ x, const float* __restrict__ Wih0,
       const float* __restrict__ bih0, const float* __restrict__ bhh0,
       uint2* __restrict__ pre0) {
  __shared__ __align__(16) float xs[16 * 516];   // [b][8t*64d], row pad +4
  const int tid = threadIdx.x, w = tid >> 6, l = tid & 63;
  const int lm = l & 15, lq = l >> 4;
  const int tile = blockIdx.x, tch = blockIdx.y;

  bf16x8 wih[4][2]; float bias[4];
#pragma unroll
  for (int i = 0; i < 4; ++i) {
    int n = ((w * 4 + i) << 4) + lm;
    wih[i][0] = load8cvt(Wih0 + n * DIN + lq * 8);
    wih[i][1] = load8cvt(Wih0 + n * DIN + 32 + lq * 8);
    bias[i] = bih0[n] + bhh0[n];
  }
  for (int slab = 0; slab < 2; ++slab) {
    const int t0 = tch * 16 + slab * 8;
    if (slab) __syncthreads();                   // xs reuse: compute done
#pragma unroll
    for (int j = 0; j < 8; ++j) {                // 2048 x 16B chunks, coalesced
      int c = j * 256 + tid;
      int b = c >> 7;                            // 128 chunks (2KB) per row
      int o = (c & 127) << 2;                    // float offset in row
      const float* gp = x + ((size_t)(tile * 16 + b) * S_LEN + t0) * DIN + o;
      *(f32x4*)(xs + b * 516 + o) = *(const f32x4*)gp;
    }
    __syncthreads();
#pragma unroll
    for (int tt = 0; tt < 8; ++tt) {
      const float* xp = xs + lm * 516 + tt * 64 + lq * 8;
      bf16x8 xa0 = load8cvt(xp);
      bf16x8 xa1 = load8cvt(xp + 32);
      uint2* dst = pre0 + ((size_t)(tile * S_LEN + t0 + tt) * 16 + w * 4) * 64 + l;
#pragma unroll
      for (int i = 0; i < 4; ++i) {
        f32x4 a = {bias[i], bias[i], bias[i], bias[i]};
        a = mfma16(xa0, wih[i][0], a);
        a = mfma16(xa1, wih[i][1], a);
        dst[(size_t)i * 64] = pk4(a);
      }
    }
  }
}

// ============ layer-pipelined recurrence: 32 WGs x 512 thr (exact R7) =======
// Stage A (WG 0-15):  h0 recurrence + g=h0@Wih1^T+b1 (shares h0 LDS reads),
//                     g in-place over consumed pre0; flag every CH steps.
// Stage B (WG 16-31): h1 recurrence from g; epilogue sigmoid@W_out.
// LDS: h ping 0 / pong 8192; B epilogue scratch 16384.
__global__ void __launch_bounds__(512, 2)
rnn_pipe2(const float* __restrict__ Whh0, const float* __restrict__ Wih1,
          const float* __restrict__ Whh1, const float* __restrict__ bih1,
          const float* __restrict__ bhh1, const float* __restrict__ Wout,
          const float* __restrict__ bout, uint2* __restrict__ pre0,
          unsigned* __restrict__ flags, float* __restrict__ out) {
  __shared__ __align__(16) char smem[17408];

  const int tid = threadIdx.x, w = tid >> 6, l = tid & 63;
  const int lm = l & 15, lq = l >> 4;
  const int role = blockIdx.x >> 4;       // 0=A (layer0+g), 1=B (layer1)
  const int tile = blockIdx.x & 15;       // A(t),B(t) same XCD (%8)

  const int lbase = l << 4;
  const int wbase = frag_off(w * 32 + lm, lq << 2);
  uint2* pb = pre0 + (size_t)tile * (S_LEN * 1024) + w * 128 + l;
  unsigned* flag = flags + tile;

  if (role == 0) {
    // ================= Stage A: h0 recurrence + g producer ==================
    bf16x8 whh0[2][8], wih1[2][8];
    float bias1[2];
#pragma unroll
    for (int i = 0; i < 2; ++i) {
      int n = ((w * 2 + i) << 4) + lm;
#pragma unroll
      for (int kt = 0; kt < 8; ++kt) {
        whh0[i][kt] = load8cvt(Whh0 + n * HDIM + kt * 32 + lq * 8);
        wih1[i][kt] = load8cvt(Wih1 + n * HDIM + kt * 32 + lq * 8);
      }
      bias1[i] = bih1[n] + bhh1[n];
    }
    uint2 bufA[2], bufB[2];
    bufA[0] = pb[0];    bufA[1] = pb[64];        // pre[0]
    bufB[0] = pb[1024]; bufB[1] = pb[1024 + 64]; // pre[1]

    // phase 0 (peeled): h0[0] = tanh(pre[0]) into parity-0 buffer
    {
#pragma unroll
      for (int i = 0; i < 2; ++i) {
        f32x4 a = unpk4(bufA[i]);
#pragma unroll
        for (int r = 0; r < 4; ++r)
          *(short*)(smem + wbase + i * 512 + r * 16) = f2bf(fast_tanh(a[r]));
      }
      const uint2* np = pb + (size_t)2 * 1024;   // prefetch pre[2]
      bufA[0] = np[0]; bufA[1] = np[64];
      bar_lds();
    }

    // phase p: h0[p] = tanh(pre[p] + h0[p-1]Whh0^T), g[p-1] = h0[p-1]Wih1^T+b1
    auto phaseA = [&](int p, int pbit, uint2 (&buf)[2]) {
      const int h0r = (pbit ^ 1) * 8192;
      const int h0w = pbit * 8192;
      f32x4 a0 = unpk4(buf[0]), a1 = unpk4(buf[1]);
      f32x4 g0 = {bias1[0], bias1[0], bias1[0], bias1[0]};
      f32x4 g1 = {bias1[1], bias1[1], bias1[1], bias1[1]};
#pragma unroll
      for (int kt = 0; kt < 8; ++kt) {           // shared h0[p-1] read
        bf16x8 hf = *(const bf16x8*)(smem + h0r + kt * 1024 + lbase);
        a0 = mfma16(hf, whh0[0][kt], a0);
        a1 = mfma16(hf, whh0[1][kt], a1);
        g0 = mfma16(hf, wih1[0][kt], g0);
        g1 = mfma16(hf, wih1[1][kt], g1);
      }
      {                                          // prefetch pre[p+2] (clamped)
        int tn = (p + 2 < S_LEN) ? p + 2 : S_LEN - 1;
        const uint2* np = pb + (size_t)tn * 1024;
        buf[0] = np[0]; buf[1] = np[64];
      }
#pragma unroll
      for (int i = 0; i < 2; ++i) {              // write h0[p] to LDS
        f32x4 a = i ? a1 : a0;
#pragma unroll
        for (int r = 0; r < 4; ++r)
          *(short*)(smem + h0w + wbase + i * 512 + r * 16) = f2bf(fast_tanh(a[r]));
      }
      {                                          // g[p-1] in-place over pre0
        uint2* gd = pb + (size_t)(p - 1) * 1024;
        gd[0] = pk4(g0); gd[64] = pk4(g1);
      }
      if ((p & (CH - 1)) == 0) {                 // chunk p/CH-1 complete:
        __builtin_amdgcn_fence(__ATOMIC_RELEASE, "agent");  // drains stores
        __syncthreads();                         // all waves fenced
        if (tid == 0) st_rlx(flag, (unsigned)(p >> 6));
      } else {
        bar_lds();                               // LDS-only handoff: vmcnt
      }                                          // stays in flight
    };

    for (int p = 1; p + 1 < S_LEN; p += 2) {
      phaseA(p, 1, bufB);
      phaseA(p + 1, 0, bufA);
    }
    phaseA(S_LEN - 1, 1, bufB);                  // p = 2047

    // tail: g[S-1] = h0[S-1]Wih1^T + b1  (h0[2047] at parity 1)
    {
      f32x4 g0 = {bias1[0], bias1[0], bias1[0], bias1[0]};
      f32x4 g1 = {bias1[1], bias1[1], bias1[1], bias1[1]};
#pragma unroll
      for (int kt = 0; kt < 8; ++kt) {
        bf16x8 hf = *(const bf16x8*)(smem + 8192 + kt * 1024 + lbase);
        g0 = mfma16(hf, wih1[0][kt], g0);
        g1 = mfma16(hf, wih1[1][kt], g1);
      }
      uint2* gd = pb + (size_t)(S_LEN - 1) * 1024;
      gd[0] = pk4(g0); gd[64] = pk4(g1);
      __builtin_amdgcn_fence(__ATOMIC_RELEASE, "agent");
      __syncthreads();
      if (tid == 0) st_rlx(flag, (unsigned)(S_LEN / CH));   // = 32
    }

  } else {
    // ================= Stage B: h1 recurrence + output ======================
    bf16x8 whh1[2][8];
#pragma unroll
    for (int i = 0; i < 2; ++i) {
      int n = ((w * 2 + i) << 4) + lm;
#pragma unroll
      for (int kt = 0; kt < 8; ++kt)
        whh1[i][kt] = load8cvt(Whh1 + n * HDIM + kt * 32 + lq * 8);
    }
    // zero h1[-1] (parity-1 buffer at 8192): 512 thr x 16B = 8KB
    ((f32x4*)(smem + 8192))[tid] = (f32x4){0.f, 0.f, 0.f, 0.f};
    __syncthreads();

    uint2 gcur[2], gnxt[2];
    unsigned have = 0;
    unsigned budget = 4000000u;                  // bounded spin; never hang

    auto stepB = [&](int t, int pbit) {
      const int h1r = (pbit ^ 1) * 8192;
      const int h1w = pbit * 8192;
      const bool pf = ((t & (CH - 1)) != CH - 1);  // next g within this chunk
      if (pf) {
        const uint2* np = pb + (size_t)(t + 1) * 1024;
        gnxt[0] = np[0]; gnxt[1] = np[64];
      }
      f32x4 c0 = unpk4(gcur[0]), c1 = unpk4(gcur[1]);
#pragma unroll
      for (int kt = 0; kt < 8; ++kt) {
        bf16x8 hf = *(const bf16x8*)(smem + h1r + kt * 1024 + lbase);
        c0 = mfma16(hf, whh1[0][kt], c0);
        c1 = mfma16(hf, whh1[1][kt], c1);
      }
#pragma unroll
      for (int i = 0; i < 2; ++i) {
        f32x4 c = i ? c1 : c0;
#pragma unroll
        for (int r = 0; r < 4; ++r)
          *(short*)(smem + h1w + wbase + i * 512 + r * 16) = f2bf(fast_tanh(c[r]));
      }
      if (pf) { gcur[0] = gnxt[0]; gcur[1] = gnxt[1]; }
      bar_lds();                                   // LDS-only handoff
    };

    for (int c = 0; c < S_LEN / CH; ++c) {
      while (have < (unsigned)(c + 1)) {           // per-chunk acquire wait
        have = ld_acq(flag);
        if (have < (unsigned)(c + 1)) {
          __builtin_amdgcn_s_sleep(8);
          if (--budget == 0u) { have = (unsigned)(c + 1); }
        }
      }
      const int t0 = c * CH;
      { const uint2* np = pb + (size_t)t0 * 1024; gcur[0] = np[0]; gcur[1] = np[64]; }
      for (int tt = 0; tt < CH; tt += 2) {
        stepB(t0 + tt, 0);
        stepB(t0 + tt + 1, 1);
      }
    }

    // epilogue: out = sigmoid(h1[S-1] @ W_out^T + b_out); h1[2047] at 8192
    if (tid < 256) {
      int m = tid >> 4, j = tid & 15;
      float s = 0.f;
#pragma unroll
      for (int kk = 0; kk < 16; ++kk) {
        int k = j * 16 + kk;
        s += bf2f(*(unsigned short*)(smem + 8192 + frag_off(k, m))) * Wout[k];
      }
      ((float*)(smem + 16384))[(m << 4) + j] = s;
    }
    __syncthreads();
    if (tid < 16) {
      float s = 0.f;
#pragma unroll
      for (int j = 0; j < 16; ++j) s += ((float*)(smem + 16384))[(tid << 4) + j];
      s += bout[0];
      out[(tile << 4) + tid] = 1.f / (1.f + __expf(-s));
    }
  }
}

// ============ fallback (ws too small for flags): R5 single-stage ============
__global__ void __launch_bounds__(512, 2)
rnn_pre8(const float* __restrict__ Whh0, const float* __restrict__ Wih1,
         const float* __restrict__ Whh1, const float* __restrict__ bih1,
         const float* __restrict__ bhh1, const float* __restrict__ Wout,
         const float* __restrict__ bout, const uint2* __restrict__ pre0,
         float* __restrict__ out) {
  __shared__ __align__(16) char smem[33792];

  const int tid = threadIdx.x, w = tid >> 6, l = tid & 63;
  const int lm = l & 15, lq = l >> 4;
  const int tile = blockIdx.x;

  bf16x8 whh0[2][8], wih1[2][8], whh1[2][8];
  float bias1[2];
#pragma unroll
  for (int i = 0; i < 2; ++i) {
    int n = ((w * 2 + i) << 4) + lm;
#pragma unroll
    for (int kt = 0; kt < 8; ++kt) {
      whh0[i][kt] = load8cvt(Whh0 + n * HDIM + kt * 32 + lq * 8);
      wih1[i][kt] = load8cvt(Wih1 + n * HDIM + kt * 32 + lq * 8);
      whh1[i][kt] = load8cvt(Whh1 + n * HDIM + kt * 32 + lq * 8);
    }
    bias1[i] = bih1[n] + bhh1[n];
  }
  ((f32x4*)(smem + 24576))[tid] = (f32x4){0.f, 0.f, 0.f, 0.f};

  const int lbase = l << 4;
  const int wbase = frag_off(w * 32 + lm, lq << 2);
  const uint2* pbase = pre0 + (size_t)tile * (S_LEN * 1024) + w * 128 + l;
  uint2 bufA[2], bufB[2];
  bufA[0] = pbase[0];    bufA[1] = pbase[64];
  bufB[0] = pbase[1024]; bufB[1] = pbase[1024 + 64];

  {
#pragma unroll
    for (int i = 0; i < 2; ++i) {
      f32x4 a = unpk4(bufA[i]);
#pragma unroll
      for (int r = 0; r < 4; ++r)
        *(short*)(smem + wbase + i * 512 + r * 16) = f2bf(fast_tanh(a[r]));
    }
    const uint2* np = pbase + (size_t)2 * 1024;
    bufA[0] = np[0]; bufA[1] = np[64];
    bar_lds();
  }

  auto phase = [&](int p, int pbit, uint2 (&buf)[2]) {
    const int h0r_o = (pbit ^ 1) * 8192;
    const int h0w_o = pbit * 8192;
    const int h1r_o = 16384 + pbit * 8192;
    const int h1w_o = 16384 + (pbit ^ 1) * 8192;

    f32x4 a0 = unpk4(buf[0]), a1 = unpk4(buf[1]);
    f32x4 c0 = {bias1[0], bias1[0], bias1[0], bias1[0]};
    f32x4 c1 = {bias1[1], bias1[1], bias1[1], bias1[1]};
#pragma unroll
    for (int kt = 0; kt < 8; ++kt) {
      bf16x8 hf = *(const bf16x8*)(smem + h0r_o + kt * 1024 + lbase);
      a0 = mfma16(hf, whh0[0][kt], a0);
      a1 = mfma16(hf, whh0[1][kt], a1);
      c0 = mfma16(hf, wih1[0][kt], c0);
      c1 = mfma16(hf, wih1[1][kt], c1);
    }
#pragma unroll
    for (int kt = 0; kt < 8; ++kt) {
      bf16x8 hf = *(const bf16x8*)(smem + h1r_o + kt * 1024 + lbase);
      c0 = mfma16(hf, whh1[0][kt], c0);
      c1 = mfma16(hf, whh1[1][kt], c1);
    }
#pragma unroll
    for (int i = 0; i < 2; ++i) {
      f32x4 a = i ? a1 : a0;
      f32x4 c = i ? c1 : c0;
#pragma unroll
      for (int r = 0; r < 4; ++r) {
        *(short*)(smem + h0w_o + wbase + i * 512 + r * 16) = f2bf(fast_tanh(a[r]));
        *(short*)(smem + h1w_o + wbase + i * 512 + r * 16) = f2bf(fast_tanh(c[r]));
      }
    }
    {
      int tn = (p + 2 < S_LEN) ? p + 2 : S_LEN - 1;
      const uint2* np = pbase + (size_t)tn * 1024;
      buf[0] = np[0]; buf[1] = np[64];
    }
    bar_lds();
  };

  for (int p = 1; p + 1 < S_LEN; p += 2) {
    phase(p, 1, bufB);
    phase(p + 1, 0, bufA);
  }
  phase(S_LEN - 1, 1, bufB);

  {
    f32x4 c0 = {bias1[0], bias1[0], bias1[0], bias1[0]};
    f32x4 c1 = {bias1[1], bias1[1], bias1[1], bias1[1]};
#pragma unroll
    for (int kt = 0; kt < 8; ++kt) {
      bf16x8 hf = *(const bf16x8*)(smem + 8192 + kt * 1024 + lbase);
      c0 = mfma16(hf, wih1[0][kt], c0);
      c1 = mfma16(hf, wih1[1][kt], c1);
    }
#pragma unroll
    for (int kt = 0; kt < 8; ++kt) {
      bf16x8 hf = *(const bf16x8*)(smem + 16384 + kt * 1024 + lbase);
      c0 = mfma16(hf, whh1[0][kt], c0);
      c1 = mfma16(hf, whh1[1][kt], c1);
    }
#pragma unroll
    for (int i = 0; i < 2; ++i) {
      f32x4 c = i ? c1 : c0;
#pragma unroll
      for (int r = 0; r < 4; ++r)
        *(short*)(smem + 24576 + wbase + i * 512 + r * 16) = f2bf(fast_tanh(c[r]));
    }
    __syncthreads();
  }

  if (tid < 256) {
    int m = tid >> 4, j = tid & 15;
    float s = 0.f;
#pragma unroll
    for (int kk = 0; kk < 16; ++kk) {
      int k = j * 16 + kk;
      s += bf2f(*(unsigned short*)(smem + 24576 + frag_off(k, m))) * Wout[k];
    }
    ((float*)(smem + 32768))[(m << 4) + j] = s;
  }
  __syncthreads();
  if (tid < 16) {
    float s = 0.f;
#pragma unroll
    for (int j = 0; j < 16; ++j) s += ((float*)(smem + 32768))[(tid << 4) + j];
    s += bout[0];
    out[(tile << 4) + tid] = 1.f / (1.f + __expf(-s));
  }
}

extern "C" void kernel_launch(void* const* d_in, const int* in_sizes, int n_in,
                              void* d_out, int out_size, void* d_ws, size_t ws_size,
                              hipStream_t stream) {
  (void)in_sizes; (void)n_in; (void)out_size;
  const float* x    = (const float*)d_in[0];
  const float* Wih0 = (const float*)d_in[1];
  const float* Whh0 = (const float*)d_in[2];
  const float* bih0 = (const float*)d_in[3];
  const float* bhh0 = (const float*)d_in[4];
  const float* Wih1 = (const float*)d_in[5];
  const float* Whh1 = (const float*)d_in[6];
  const float* bih1 = (const float*)d_in[7];
  const float* bhh1 = (const float*)d_in[8];
  const float* Wout = (const float*)d_in[9];
  const float* bout = (const float*)d_in[10];

  const size_t PRE_BYTES = (size_t)16 * S_LEN * 16 * 64 * 8;  // 268 MB

  x_proj<<<dim3(16, 128), dim3(256), 0, stream>>>(x, Wih0, bih0, bhh0,
                                                  (uint2*)d_ws);
  if (ws_size >= PRE_BYTES + 4096) {
    unsigned* flags = (unsigned*)((char*)d_ws + PRE_BYTES);
    zero_flags<<<dim3(1), dim3(64), 0, stream>>>(flags);
    rnn_pipe2<<<dim3(32), dim3(512), 0, stream>>>(
        Whh0, Wih1, Whh1, bih1, bhh1, Wout, bout, (uint2*)d_ws, flags,
        (float*)d_out);
  } else {
    rnn_pre8<<<dim3(16), dim3(512), 0, stream>>>(
        Whh0, Wih1, Whh1, bih1, bhh1, Wout, bout, (const uint2*)d_ws,
        (float*)d_out);
  }
}